// Round 9
// baseline (340.843 us; speedup 1.0000x reference)
//
#include <hip/hip_runtime.h>
#include <hip/hip_bf16.h>
#include <stdint.h>

typedef __attribute__((ext_vector_type(8))) __bf16 bf16x8;
typedef __attribute__((ext_vector_type(4))) float f32x4;

constexpr int K_DIM = 4096;
constexpr int N_DIM = 11008;
constexpr int M_DIM = 256;   // B*S
constexpr int TM = 128;      // M rows per block (halved -> halves A traffic)
constexpr int TN = 128;      // N cols per block
constexpr int BK = 64;       // K per tile
constexpr int NT = 512;      // 8 waves: 2M x 4N, each wave 64M x 32N
constexpr int KT_ALL = K_DIM / BK;   // 64
constexpr int KSPLIT = 3;    // grid = 86 x 3 x 2 = 516 ~ 2 blocks/CU
constexpr int NB = N_DIM / TN;       // 86
constexpr int WTILE = TN * BK;       // 8192 int8 = 8 KB per packed W tile

__device__ __forceinline__ void gload_lds16(const __bf16* gptr, __bf16* lptr) {
  __builtin_amdgcn_global_load_lds(
      (const __attribute__((address_space(1))) uint32_t*)gptr,
      (__attribute__((address_space(3))) uint32_t*)lptr, 16, 0, 0);
}

__device__ __forceinline__ bf16x8 cvt8f(const float4 u0, const float4 u1) {
  bf16x8 v;
  v[0] = (__bf16)u0.x; v[1] = (__bf16)u0.y; v[2] = (__bf16)u0.z; v[3] = (__bf16)u0.w;
  v[4] = (__bf16)u1.x; v[5] = (__bf16)u1.y; v[6] = (__bf16)u1.z; v[7] = (__bf16)u1.w;
  return v;
}
__device__ __forceinline__ bf16x8 cvt8i(const int4 a, const int4 b) {
  bf16x8 v;
  v[0] = (__bf16)(float)a.x; v[1] = (__bf16)(float)a.y;
  v[2] = (__bf16)(float)a.z; v[3] = (__bf16)(float)a.w;
  v[4] = (__bf16)(float)b.x; v[5] = (__bf16)(float)b.y;
  v[6] = (__bf16)(float)b.z; v[7] = (__bf16)(float)b.w;
  return v;
}

// x fp32 [256][4096] -> xws bf16 row-major (coalesced both sides). ~2 us.
__global__ void cvt_x_kernel(const float* __restrict__ x, __bf16* __restrict__ ws) {
  const int i = (blockIdx.x * 256 + threadIdx.x) * 8;
  const float4 u0 = ((const float4*)(x + i))[0];
  const float4 u1 = ((const float4*)(x + i))[1];
  *(bf16x8*)(ws + i) = cvt8f(u0, u1);
}

// w int32 [11008][4096] (int8-widened) -> wp TRUE int8, tile-major:
// wp[nb][kt] = 8 KB tile (128 N-rows x 64 K-cols), elem (r,c) at r*64+c.
// 180 MB -> 45 MB. Thread j: out bytes [j*32, j*32+32), reads 32
// consecutive int32 (128 B, one L2 line; w is L3-hot from harness restore).
__global__ void pack_w_kernel(const int* __restrict__ w, int8_t* __restrict__ wp) {
  const int j = blockIdx.x * 256 + threadIdx.x;    // 1,409,024 threads
  const size_t e = (size_t)j * 32;                 // out byte index
  const int tile = (int)(e >> 13);                 // 8 KB tiles
  const int o = (int)(e & 8191);
  const int row = o >> 6;                          // 0..127 (N within tile)
  const int col0 = o & 63;                         // 0 or 32 (K within tile)
  const int nb = tile >> 6, kt = tile & 63;
  const int4* src = (const int4*)(w + (int64_t)(nb * TN + row) * K_DIM + kt * BK + col0);
  int pk[8];
#pragma unroll
  for (int q = 0; q < 8; ++q) {
    const int4 a = src[q];
    pk[q] = (a.x & 0xFF) | ((a.y & 0xFF) << 8) | ((a.z & 0xFF) << 16) | (a.w << 24);
  }
  int4* dst = (int4*)(wp + e);
  dst[0] = make_int4(pk[0], pk[1], pk[2], pk[3]);
  dst[1] = make_int4(pk[4], pk[5], pk[6], pk[7]);
}

template<bool A_WS, bool W_PK>
__global__ __launch_bounds__(NT, 4) void int8_linear_kernel(
    const float* __restrict__ x,     // [256,4096] fp32 (fallback)
    const __bf16* __restrict__ xws,  // [256,4096] bf16 (A_WS)
    const int*   __restrict__ w,     // [11008,4096] int32 (fallback)
    const int8_t* __restrict__ wp,   // packed tile-major int8 (W_PK)
    const float* __restrict__ scale, // [11008]
    const float* __restrict__ bias,  // [11008]
    float*       __restrict__ out)   // [256,11008] fp32, pre-zeroed, atomics
{
  // R7 structure, re-tiled: TM=128 halves A traffic (the dominant byte
  // stream); TN=128 keeps the same MFMA work per block. One barrier per
  // phase; W loads to regs before compute, unpack+commit after (proven
  // split); A via fire-and-forget gload_lds, source-swizzled (rule #21).
  __shared__ __bf16 As[2][TM * BK];      // 2 x 16 KB
  __shared__ __bf16 Wsh[2][TN * BK];     // 2 x 16 KB  -> 64 KB, 2 blocks/CU

  const int tid  = threadIdx.x;
  const int lane = tid & 63;
  const int wv   = tid >> 6;
  const int quad = lane >> 4;
  const int l16  = lane & 15;
  const int m_base = (wv >> 2) * 64;   // 2 M-groups of 64
  const int wn     = wv & 3;           // 4 N-groups of 32
  const int nb     = blockIdx.x;       // N-block 0..85
  const int n_base = nb * TN;
  const int kc     = blockIdx.y;       // K-split 0..2
  const int mb     = blockIdx.z;       // M-block 0..1

  // split-K tile range over 64 tiles: {21,21,22}
  const int t0 = (kc * KT_ALL) / KSPLIT;
  const int t1 = ((kc + 1) * KT_ALL) / KSPLIT;
  const int ntile = t1 - t0;

  // W LDS geometry: thread owns 16 packed int8 = row wrow, chunks 2*wc2, +1
  const int wrow = tid >> 2;           // 0..127
  const int wc2  = tid & 3;            // chunk pair index

  f32x4 acc[4][2];
#pragma unroll
  for (int i = 0; i < 4; ++i)
#pragma unroll
    for (int j = 0; j < 2; ++j) acc[i][j] = (f32x4){0.f, 0.f, 0.f, 0.f};

  uint4 pw;        // 16 packed int8 of W in flight
  int4 wi[4];      // fallback (int32 direct)
  auto wload = [&](int t) {
    if (W_PK) {
      pw = *(const uint4*)(wp + (size_t)(nb * KT_ALL + t0 + t) * WTILE + tid * 16);
    } else {
      const int4* p = (const int4*)(w + (int64_t)(n_base + wrow) * K_DIM +
                                    (t0 + t) * BK + wc2 * 16);
#pragma unroll
      for (int q = 0; q < 4; ++q) wi[q] = p[q];
    }
  };
  auto commitW = [&](__bf16* wbuf) {
#pragma unroll
    for (int h = 0; h < 2; ++h) {      // two 8-byte chunks
      bf16x8 v;
      const uint32_t lo = h ? pw.z : pw.x;
      const uint32_t hi = h ? pw.w : pw.y;
      if (W_PK) {
#pragma unroll
        for (int e = 0; e < 4; ++e)
          v[e] = (__bf16)(float)(int)(int8_t)((lo >> (8 * e)) & 0xFF);
#pragma unroll
        for (int e = 0; e < 4; ++e)
          v[4 + e] = (__bf16)(float)(int)(int8_t)((hi >> (8 * e)) & 0xFF);
      } else {
        v = cvt8i(wi[h * 2], wi[h * 2 + 1]);
      }
      const int chunk = wc2 * 2 + h;
      *(bf16x8*)(wbuf + wrow * BK + (chunk ^ (wrow & 7)) * 8) = v;
    }
  };
  // A: 1024 16B-chunks / 512 thr = 2 gload_lds each; source-swizzled,
  // L2-resident (xws = 2 MB).
  auto a_stage = [&](int t, __bf16* abuf) {
    const int kt = t0 + t;
    if (A_WS) {
#pragma unroll
      for (int j = 0; j < 2; ++j) {
        const int c = j * 512 + tid;
        const int row = c >> 3;
        const int k8 = (c & 7) ^ (row & 7);
        gload_lds16(xws + (int64_t)(mb * TM + row) * K_DIM + kt * BK + k8 * 8,
                    abuf + c * 8);
      }
    } else {
#pragma unroll
      for (int j = 0; j < 2; ++j) {
        const int c = j * 512 + tid;
        const int row = c >> 3;
        const int k8 = c & 7;
        const float* s = x + (int64_t)(mb * TM + row) * K_DIM + kt * BK + k8 * 8;
        const bf16x8 vv = cvt8f(((const float4*)s)[0], ((const float4*)s)[1]);
        *(bf16x8*)(abuf + row * BK + (k8 ^ (row & 7)) * 8) = vv;
      }
    }
  };
  auto compute = [&](const __bf16* abuf, const __bf16* wbuf) {
#pragma unroll
    for (int ks = 0; ks < 2; ++ks) {
      bf16x8 a[4], b[2];
#pragma unroll
      for (int mi = 0; mi < 4; ++mi) {
        const int m = m_base + mi * 16 + l16;
        const int slot = (ks * 4 + quad) ^ (m & 7);
        a[mi] = *(const bf16x8*)(abuf + m * BK + slot * 8);
      }
#pragma unroll
      for (int ni = 0; ni < 2; ++ni) {
        const int n = wn * 32 + ni * 16 + l16;
        const int slot = (ks * 4 + quad) ^ (n & 7);
        b[ni] = *(const bf16x8*)(wbuf + n * BK + slot * 8);
      }
#pragma unroll
      for (int mi = 0; mi < 4; ++mi)
#pragma unroll
        for (int ni = 0; ni < 2; ++ni)
          acc[mi][ni] = __builtin_amdgcn_mfma_f32_16x16x32_bf16(
              a[mi], b[ni], acc[mi][ni], 0, 0, 0);
    }
  };

  // Prologue: tile 0 staged (W via regs->LDS, A via gload_lds).
  wload(0);
  commitW(Wsh[0]);
  a_stage(0, As[0]);
  __syncthreads();

  // 2-barrier double-buffered loop: loads for t+1 issue BEFORE compute(t);
  // W unpack+commit lands AFTER compute, before the barrier.
  for (int t = 0; t < ntile; ++t) {
    const int nxt = (t + 1) & 1;
    const bool more = (t + 1 < ntile);
    if (more) { wload(t + 1); a_stage(t + 1, As[nxt]); }
    compute(As[t & 1], Wsh[t & 1]);
    if (more) commitW(Wsh[nxt]);
    __syncthreads();
  }

  // Epilogue: C/D layout col=lane&15, row=quad*4+reg (m89-verified).
  // Scale per-partial (linear); bias added exactly once by the kc==0 block.
#pragma unroll
  for (int ni = 0; ni < 2; ++ni) {
    const int col = n_base + wn * 32 + ni * 16 + l16;
    const float sc = scale[col];
    const float bi = (kc == 0) ? bias[col] : 0.0f;
#pragma unroll
    for (int mi = 0; mi < 4; ++mi) {
      const int row0 = mb * TM + m_base + mi * 16 + quad * 4;
#pragma unroll
      for (int r = 0; r < 4; ++r)
        unsafeAtomicAdd(out + (int64_t)(row0 + r) * N_DIM + col,
                        acc[mi][ni][r] * sc + bi);
    }
  }
}

extern "C" void kernel_launch(void* const* d_in, const int* in_sizes, int n_in,
                              void* d_out, int out_size, void* d_ws, size_t ws_size,
                              hipStream_t stream) {
  const float* x     = (const float*)d_in[0];
  const int*   w     = (const int*)d_in[1];
  const float* scale = (const float*)d_in[2];
  const float* bias  = (const float*)d_in[3];
  float* out = (float*)d_out;

  const size_t xws_bytes = (size_t)M_DIM * K_DIM * sizeof(__bf16);   // 2 MB
  const size_t wp_bytes  = (size_t)N_DIM * K_DIM;                    // 45 MB
  __bf16* xws = (__bf16*)d_ws;
  int8_t* wpp = (int8_t*)((char*)d_ws + xws_bytes);

  // split-K partials accumulate via atomics -> zero the output first
  hipMemsetAsync(out, 0, (size_t)M_DIM * N_DIM * sizeof(float), stream);

  dim3 grid(NB, KSPLIT, M_DIM / TM), block(NT);
  if (ws_size >= xws_bytes + wp_bytes) {
    cvt_x_kernel<<<M_DIM * K_DIM / 2048, 256, 0, stream>>>(x, xws);
    pack_w_kernel<<<(int)(((size_t)N_DIM * K_DIM / 32) / 256), 256, 0, stream>>>(w, wpp);
    int8_linear_kernel<true, true><<<grid, block, 0, stream>>>(
        x, xws, w, wpp, scale, bias, out);
  } else if (ws_size >= xws_bytes) {
    cvt_x_kernel<<<M_DIM * K_DIM / 2048, 256, 0, stream>>>(x, xws);
    int8_linear_kernel<true, false><<<grid, block, 0, stream>>>(
        x, xws, w, wpp, scale, bias, out);
  } else {
    int8_linear_kernel<false, false><<<grid, block, 0, stream>>>(
        x, xws, w, wpp, scale, bias, out);
  }
}